// Round 1
// baseline (1562.144 us; speedup 1.0000x reference)
//
#include <hip/hip_runtime.h>
#include <hip/hip_bf16.h>

#define NNODES 60000
#define NREL   70
#define NB     30
#define NEDGE  1920000

// ---------------- CSR build ----------------

__global__ void hist_kernel(const int* __restrict__ dst, int* __restrict__ cnt) {
    int e = blockIdx.x * blockDim.x + threadIdx.x;
    if (e < NEDGE) atomicAdd(&cnt[dst[e]], 1);
}

// single-workgroup chunked exclusive scan of cnt[0..n) -> offs[0..n]
__global__ void scan_kernel(const int* __restrict__ cnt, int* __restrict__ offs, int n) {
    __shared__ int lds[1024];
    __shared__ int carry_s;
    int tid = threadIdx.x;
    if (tid == 0) carry_s = 0;
    __syncthreads();
    for (int base = 0; base < n; base += 1024) {
        int v = (base + tid < n) ? cnt[base + tid] : 0;
        lds[tid] = v;
        __syncthreads();
        for (int d = 1; d < 1024; d <<= 1) {
            int t = (tid >= d) ? lds[tid - d] : 0;
            __syncthreads();
            lds[tid] += t;
            __syncthreads();
        }
        int incl  = lds[tid];
        int total = lds[1023];
        int carry = carry_s;
        __syncthreads();
        if (base + tid < n) offs[base + tid] = carry + incl - v;  // exclusive
        if (tid == 0) carry_s = carry + total;
        __syncthreads();
    }
    if (tid == 0) offs[n] = carry_s;
}

__global__ void fill_kernel(const int* __restrict__ src, const int* __restrict__ dst,
                            const int* __restrict__ et, const int* __restrict__ offs,
                            int* __restrict__ cursor, int* __restrict__ ebuf) {
    int e = blockIdx.x * blockDim.x + threadIdx.x;
    if (e < NEDGE) {
        int d   = dst[e];
        int pos = atomicAdd(&cursor[d], 1);
        ebuf[offs[d] + pos] = (et[e] << 16) | src[e];   // src < 65536, et < 70
    }
}

// ---------------- weight expansion: w[r] = sum_b att[r,b] * basis[b] ----------------

__global__ void wexpand_kernel(const float* __restrict__ att, const float* __restrict__ basis,
                               float* __restrict__ w, int rio, int total) {
    int idx = blockIdx.x * blockDim.x + threadIdx.x;
    if (idx >= total) return;
    int r = idx / rio, t = idx - r * rio;
    float s = 0.f;
    #pragma unroll
    for (int b = 0; b < NB; ++b) s += att[r * NB + b] * basis[b * rio + t];
    w[idx] = s;
}

// ---------------- layer 1: identity features ----------------
// x1[n,o] = relu( mean_{e->n} sum_b att1[et,b]*basis1[b,src,o] + root1[n,o] + bias1[o] )
// block = 256 (4 waves), one node per wave; lanes: o = lane&31, two edge halves.

__global__ void layer1_kernel(const int* __restrict__ ebuf, const int* __restrict__ offs,
                              const int* __restrict__ cnt,
                              const float* __restrict__ att1, const float* __restrict__ basis1,
                              const float* __restrict__ root1, const float* __restrict__ bias1,
                              float* __restrict__ x1) {
    int wave = threadIdx.x >> 6;
    int lane = threadIdx.x & 63;
    int n = blockIdx.x * 4 + wave;
    if (n >= NNODES) return;
    int o    = lane & 31;
    int half = lane >> 5;
    int off  = offs[n];
    int c    = cnt[n];
    float acc = 0.f;
    for (int k = 0; k < c; k += 2) {
        int kk = k + half;
        if (kk < c) {
            int packed = ebuf[off + kk];
            int src = packed & 0xFFFF;
            int et  = packed >> 16;
            const float* bptr = basis1 + (size_t)src * 32 + o;
            const float* aptr = att1 + et * NB;
            #pragma unroll
            for (int b = 0; b < NB; ++b)
                acc += aptr[b] * bptr[(size_t)b * NNODES * 32];
        }
    }
    acc += __shfl_xor(acc, 32);
    if (half == 0) {
        float v = acc / fmaxf((float)c, 1.0f) + root1[(size_t)n * 32 + o] + bias1[o];
        x1[(size_t)n * 32 + o] = fmaxf(v, 0.0f);
    }
}

// ---------------- layer 2: in=32 out=8 ----------------
// lanes: o = lane&7, slot = lane>>3 (8 edges in flight per wave)

__global__ void layer2_kernel(const int* __restrict__ ebuf, const int* __restrict__ offs,
                              const int* __restrict__ cnt,
                              const float* __restrict__ x1, const float* __restrict__ w2,
                              const float* __restrict__ root2, const float* __restrict__ bias2,
                              float* __restrict__ x2) {
    int wave = threadIdx.x >> 6;
    int lane = threadIdx.x & 63;
    int n = blockIdx.x * 4 + wave;
    if (n >= NNODES) return;
    int o    = lane & 7;
    int slot = lane >> 3;
    int off  = offs[n];
    int c    = cnt[n];
    float acc = 0.f;
    for (int k0 = 0; k0 < c; k0 += 8) {
        int kk = k0 + slot;
        if (kk < c) {
            int packed = ebuf[off + kk];
            int src = packed & 0xFFFF;
            int et  = packed >> 16;
            const float* xp = x1 + (size_t)src * 32;
            const float* wp = w2 + et * 256 + o;
            #pragma unroll
            for (int i = 0; i < 32; ++i)
                acc += xp[i] * wp[i * 8];
        }
    }
    #pragma unroll
    for (int d = 8; d < 64; d <<= 1) acc += __shfl_xor(acc, d);
    if (lane < 8) {
        float self = 0.f;
        const float* xn = x1 + (size_t)n * 32;
        #pragma unroll
        for (int i = 0; i < 32; ++i) self += xn[i] * root2[i * 8 + o];
        float v = acc / fmaxf((float)c, 1.0f) + self + bias2[o];
        x2[(size_t)n * 8 + o] = fmaxf(v, 0.0f);
    }
}

// ---------------- layer 3: in=8 out=1 ----------------

__global__ void layer3_kernel(const int* __restrict__ ebuf, const int* __restrict__ offs,
                              const int* __restrict__ cnt,
                              const float* __restrict__ x2, const float* __restrict__ w3,
                              const float* __restrict__ root3, const float* __restrict__ bias3,
                              float* __restrict__ out) {
    int wave = threadIdx.x >> 6;
    int lane = threadIdx.x & 63;
    int n = blockIdx.x * 4 + wave;
    if (n >= NNODES) return;
    int off = offs[n];
    int c   = cnt[n];
    float acc = 0.f;
    for (int k = lane; k < c; k += 64) {
        int packed = ebuf[off + k];
        int src = packed & 0xFFFF;
        int et  = packed >> 16;
        const float* xp = x2 + (size_t)src * 8;
        const float* wp = w3 + et * 8;
        #pragma unroll
        for (int i = 0; i < 8; ++i) acc += xp[i] * wp[i];
    }
    #pragma unroll
    for (int d = 1; d < 64; d <<= 1) acc += __shfl_xor(acc, d);
    if (lane == 0) {
        float self = 0.f;
        const float* xn = x2 + (size_t)n * 8;
        #pragma unroll
        for (int i = 0; i < 8; ++i) self += xn[i] * root3[i];
        out[n] = acc / fmaxf((float)c, 1.0f) + self + bias3[0];
    }
}

// ---------------- launch ----------------

extern "C" void kernel_launch(void* const* d_in, const int* in_sizes, int n_in,
                              void* d_out, int out_size, void* d_ws, size_t ws_size,
                              hipStream_t stream) {
    const int*   edge_index = (const int*)  d_in[0];   // (2,E): row0=src, row1=dst
    const int*   edge_type  = (const int*)  d_in[1];
    const float* att1   = (const float*) d_in[2];
    const float* basis1 = (const float*) d_in[3];
    const float* root1  = (const float*) d_in[4];
    const float* bias1  = (const float*) d_in[5];
    const float* att2   = (const float*) d_in[6];
    const float* basis2 = (const float*) d_in[7];
    const float* root2  = (const float*) d_in[8];
    const float* bias2  = (const float*) d_in[9];
    const float* att3   = (const float*) d_in[10];
    const float* basis3 = (const float*) d_in[11];
    const float* root3  = (const float*) d_in[12];
    const float* bias3  = (const float*) d_in[13];
    float* out = (float*)d_out;

    const int* src = edge_index;
    const int* dst = edge_index + NEDGE;

    char* ws = (char*)d_ws;
    int*   cnt    = (int*)(ws + 0);              // 240000 B
    int*   cursor = (int*)(ws + 240128);         // 240000 B
    int*   offs   = (int*)(ws + 480256);         // 240004 B
    int*   ebuf   = (int*)(ws + 720640);         // 7,680,000 B
    float* w2     = (float*)(ws + 8400640);      // 71,680 B
    float* w3     = (float*)(ws + 8472320);      // 2,240 B
    float* x1     = (float*)(ws + 8474624);      // 7,680,000 B
    float* x2     = (float*)(ws + 16154624);     // 1,920,000 B

    // zero cnt + cursor (contiguous)
    hipMemsetAsync(ws, 0, 480256, stream);

    // CSR build
    hist_kernel<<<NEDGE / 256, 256, 0, stream>>>(dst, cnt);
    scan_kernel<<<1, 1024, 0, stream>>>(cnt, offs, NNODES);
    fill_kernel<<<NEDGE / 256, 256, 0, stream>>>(src, dst, edge_type, offs, cursor, ebuf);

    // weight expansion for layers 2, 3
    wexpand_kernel<<<(NREL * 256 + 255) / 256, 256, 0, stream>>>(att2, basis2, w2, 256, NREL * 256);
    wexpand_kernel<<<(NREL * 8 + 255) / 256, 256, 0, stream>>>(att3, basis3, w3, 8, NREL * 8);

    // layers
    layer1_kernel<<<NNODES / 4, 256, 0, stream>>>(ebuf, offs, cnt, att1, basis1, root1, bias1, x1);
    layer2_kernel<<<NNODES / 4, 256, 0, stream>>>(ebuf, offs, cnt, x1, w2, root2, bias2, x2);
    layer3_kernel<<<NNODES / 4, 256, 0, stream>>>(ebuf, offs, cnt, x2, w3, root3, bias3, out);
}